// Round 7
// baseline (728.097 us; speedup 1.0000x reference)
//
#include <hip/hip_runtime.h>
#include <hip/hip_bf16.h>

// L=4096, N=B=64. CH=8 -> CN=512 chunks (2 WG/CU on 256 CUs, exactly resident).
// Scan hierarchy: 512 chunks = 64 groups x 8 = 8 supers x 8 groups x 8.
// P stored ROW-MAJOR packed (hi<<16)|lo bf16 u32; V stored fp32 transposed.
// Wave tiling 16x64 (wave-exclusive A rows, no dup). State dbuf in LDS.
// All 5 phases fused into ONE plain kernel (graph-capturable) with a manual
// grid barrier: 4 single-use arrive counters (agent-scope atomics, zeroed by
// a captured hipMemsetAsync). 512 blocks are exactly co-resident
// (launch_bounds(256,2), 72KB LDS -> 2 blocks/CU) so spinning cannot deadlock.
#define TL 4096
#define NB 64
#define CH 8
#define CN 512
#define AS 72          // LDS row stride (bf16): 144 B (odd 16B groups -> conflict-free b128)

typedef __attribute__((ext_vector_type(8))) short short8;
typedef __attribute__((ext_vector_type(4))) short short4v;
typedef __attribute__((ext_vector_type(4))) float floatx4;
typedef __attribute__((ext_vector_type(4))) unsigned int uint4v;

__device__ inline floatx4 mfma_bf16(short8 a, short8 b, floatx4 c) {
    return __builtin_amdgcn_mfma_f32_16x16x32_bf16(a, b, c, 0, 0, 0);
}
__device__ inline short bf16_rne(float x) {
    union { __hip_bfloat16 b; unsigned short s; } u;
    u.b = __float2bfloat16(x);
    return (short)u.s;
}
// fp32 -> (hi, lo) bf16 pair. x ~= hi + lo to ~2^-17 rel.
__device__ inline void split_bf16(float x, short& h, short& l) {
    h = bf16_rne(x);
    union { unsigned u; float f; } hv; hv.u = ((unsigned)(unsigned short)h) << 16;
    l = bf16_rne(x - hv.f);
}
// 8 consecutive fp32 (2 float4) -> hi/lo bf16 fragments
__device__ inline void cvt_frag(float4 a, float4 b, short8& H, short8& L) {
    float v[8] = {a.x,a.y,a.z,a.w,b.x,b.y,b.z,b.w};
#pragma unroll
    for (int r = 0; r < 8; ++r) { short hh,ll; split_bf16(v[r],hh,ll); H[r]=hh; L[r]=ll; }
}
// 8 packed u32 (2 uint4) -> hi/lo fragments
__device__ inline void unpack_frag(uint4v a, uint4v b, short8& H, short8& L) {
#pragma unroll
    for (int r = 0; r < 4; ++r) {
        H[r]   = (short)(a[r] >> 16); L[r]   = (short)(a[r] & 0xFFFFu);
        H[4+r] = (short)(b[r] >> 16); L[4+r] = (short)(b[r] & 0xFFFFu);
    }
}

// Single-use grid barrier (counter pre-zeroed per launch via hipMemsetAsync).
// Agent-scope atomics bypass the non-coherent per-XCD L2s; threadfence
// before/after handles the plain data stores/loads around the barrier.
__device__ inline void grid_barrier(unsigned* cnt, unsigned nb) {
    __threadfence();
    __syncthreads();
    if (threadIdx.x == 0) {
        __hip_atomic_fetch_add(cnt, 1u, __ATOMIC_ACQ_REL, __HIP_MEMORY_SCOPE_AGENT);
        while (__hip_atomic_load(cnt, __ATOMIC_ACQUIRE, __HIP_MEMORY_SCOPE_AGENT) < nb)
            __builtin_amdgcn_s_sleep(2);
    }
    __syncthreads();
    __threadfence();
}

__global__ __launch_bounds__(256, 2)
void hippo_fused(const float* __restrict__ inp, const float* __restrict__ Ag,
                 const float* __restrict__ Bst, unsigned* __restrict__ P32,
                 float* __restrict__ VT, float* __restrict__ out,
                 unsigned* __restrict__ gbar)
{
    // B0: S (phase1) / Pacc (scan) / E (s3) / X (phase3).  B1: V / Vacc.
    __shared__ short B0h[2][NB][AS], B0l[2][NB][AS];
    __shared__ short B1h[2][NB][AS], B1l[2][NB][AS];

    const int tid = threadIdx.x;
    const int c = blockIdx.x, t0 = c * CH;
    const int w = tid >> 6, lane = tid & 63;
    const int quad = lane >> 4, l15 = lane & 15;
    const int arow = 16*w + l15;     // wave-exclusive A/P row
    const int wr0  = 16*w + 4*quad;  // acc row base

    // ======================= PHASE 1 =======================
    {
        float4 rA[2][2];
#pragma unroll
        for (int kc = 0; kc < 2; ++kc) {
            const float* p = Ag + (size_t)(t0+1)*4096 + (size_t)arow*64 + 32*kc + 8*quad;
            rA[kc][0] = *(const float4*)p;
            rA[kc][1] = *(const float4*)(p + 4);
        }
        float4 bnxt = *(const float4*)(Bst + (size_t)(t0+1)*64 + wr0);
        float inxt[4];
#pragma unroll
        for (int ni = 0; ni < 4; ++ni) inxt[ni] = inp[(size_t)(t0+1)*64 + l15 + 16*ni];

        floatx4 accS[4], accV[4];
        {
            const float* A0 = Ag + (size_t)t0 * 4096;
            float4 b0 = *(const float4*)(Bst + (size_t)t0*64 + wr0);
            float bc[4] = {b0.x,b0.y,b0.z,b0.w};
#pragma unroll
            for (int ni = 0; ni < 4; ++ni) {
                const float ii = inp[(size_t)t0*64 + l15 + 16*ni];
#pragma unroll
                for (int r = 0; r < 4; ++r) {
                    accS[ni][r] = A0[(size_t)(wr0 + r)*64 + l15 + 16*ni];
                    accV[ni][r] = bc[r] * ii;
                }
            }
        }
#pragma unroll
        for (int ni = 0; ni < 4; ++ni) {
            const int cc = l15 + 16*ni;
            short4v h4, l4;
#pragma unroll
            for (int r = 0; r < 4; ++r) { short hh,ll; split_bf16(accS[ni][r],hh,ll); h4[r]=hh; l4[r]=ll; }
            *(short4v*)&B0h[0][cc][wr0] = h4; *(short4v*)&B0l[0][cc][wr0] = l4;
#pragma unroll
            for (int r = 0; r < 4; ++r) { short hh,ll; split_bf16(accV[ni][r],hh,ll); h4[r]=hh; l4[r]=ll; }
            *(short4v*)&B1h[0][cc][wr0] = h4; *(short4v*)&B1l[0][cc][wr0] = l4;
        }
        __syncthreads();

        short8 aH[2], aL[2];
#pragma unroll
        for (int kc = 0; kc < 2; ++kc) cvt_frag(rA[kc][0], rA[kc][1], aH[kc], aL[kc]);

        int cur = 0;
        float4 bcur = bnxt;
        float icur[4];
#pragma unroll
        for (int ni = 0; ni < 4; ++ni) icur[ni] = inxt[ni];

        for (int s = 1; s < CH; ++s) {
            if (s + 1 < CH) {
                const int t1 = t0 + s + 1;
#pragma unroll
                for (int kc = 0; kc < 2; ++kc) {
                    const float* p = Ag + (size_t)t1*4096 + (size_t)arow*64 + 32*kc + 8*quad;
                    rA[kc][0] = *(const float4*)p;
                    rA[kc][1] = *(const float4*)(p + 4);
                }
                bnxt = *(const float4*)(Bst + (size_t)t1*64 + wr0);
#pragma unroll
                for (int ni = 0; ni < 4; ++ni) inxt[ni] = inp[(size_t)t1*64 + l15 + 16*ni];
            }
            {
                float bc[4] = {bcur.x,bcur.y,bcur.z,bcur.w};
#pragma unroll
                for (int ni = 0; ni < 4; ++ni)
#pragma unroll
                for (int r = 0; r < 4; ++r) {
                    accS[ni][r] = 0.0f;
                    accV[ni][r] = bc[r] * icur[ni];
                }
            }
#pragma unroll
            for (int kc = 0; kc < 2; ++kc) {
                const int ko = 32*kc + 8*quad;
#pragma unroll
                for (int ni = 0; ni < 4; ++ni) {
                    const int n = l15 + 16*ni;
                    short8 sH = *(const short8*)&B0h[cur][n][ko];
                    short8 sL = *(const short8*)&B0l[cur][n][ko];
                    short8 vH = *(const short8*)&B1h[cur][n][ko];
                    short8 vL = *(const short8*)&B1l[cur][n][ko];
                    accS[ni] = mfma_bf16(aH[kc], sH, accS[ni]);
                    accS[ni] = mfma_bf16(aH[kc], sL, accS[ni]);
                    accS[ni] = mfma_bf16(aL[kc], sH, accS[ni]);
                    accV[ni] = mfma_bf16(aH[kc], vH, accV[ni]);
                    accV[ni] = mfma_bf16(aH[kc], vL, accV[ni]);
                    accV[ni] = mfma_bf16(aL[kc], vH, accV[ni]);
                }
            }
            if (s + 1 < CH) {
#pragma unroll
                for (int kc = 0; kc < 2; ++kc) cvt_frag(rA[kc][0], rA[kc][1], aH[kc], aL[kc]);
                const int nb = cur ^ 1;
#pragma unroll
                for (int ni = 0; ni < 4; ++ni) {
                    const int cc = l15 + 16*ni;
                    short4v h4, l4;
#pragma unroll
                    for (int r = 0; r < 4; ++r) { short hh,ll; split_bf16(accS[ni][r],hh,ll); h4[r]=hh; l4[r]=ll; }
                    *(short4v*)&B0h[nb][cc][wr0] = h4; *(short4v*)&B0l[nb][cc][wr0] = l4;
#pragma unroll
                    for (int r = 0; r < 4; ++r) { short hh,ll; split_bf16(accV[ni][r],hh,ll); h4[r]=hh; l4[r]=ll; }
                    *(short4v*)&B1h[nb][cc][wr0] = h4; *(short4v*)&B1l[nb][cc][wr0] = l4;
                }
                __syncthreads();
                cur ^= 1;
            }
            bcur = bnxt;
#pragma unroll
            for (int ni = 0; ni < 4; ++ni) icur[ni] = inxt[ni];
        }

        unsigned* po = P32 + (size_t)c * 4096;
#pragma unroll
        for (int ni = 0; ni < 4; ++ni) {
            const int cc = l15 + 16*ni;
            *(floatx4*)(VT + (size_t)c*4096 + cc*64 + wr0) = accV[ni];
#pragma unroll
            for (int r = 0; r < 4; ++r) {
                short hh, ll; split_bf16(accS[ni][r], hh, ll);
                po[(size_t)(wr0 + r)*64 + cc] = ((unsigned)(unsigned short)hh << 16) | (unsigned)(unsigned short)ll;
            }
        }
    }

    // phase-3 t0 operand prefetch: issue BEFORE the scan interlude so HBM
    // latency hides under L1/L2/s3 (blocks are otherwise idle there).
    float4 rA3[2][2];
#pragma unroll
    for (int kc = 0; kc < 2; ++kc) {
        const float* p = Ag + (size_t)t0*4096 + (size_t)arow*64 + 32*kc + 8*quad;
        rA3[kc][0] = *(const float4*)p;
        rA3[kc][1] = *(const float4*)(p + 4);
    }
    float4 b3 = *(const float4*)(Bst + (size_t)t0*64 + wr0);
    float i3[4];
#pragma unroll
    for (int ni = 0; ni < 4; ++ni) i3[ni] = inp[(size_t)t0*64 + l15 + 16*ni];

    grid_barrier(gbar + 0, CN);

    // ======================= SCANS =======================
    auto scan8 = [&](int base, int estride) {
        {   // element 0 -> buf 0 (transpose scatter for P, row copy for V)
            const unsigned* p0 = P32 + (size_t)base * 4096;
            const float*    v0 = VT  + (size_t)base * 4096;
#pragma unroll
            for (int q = 0; q < 4; ++q) {
                int f = tid + q * 256;
                int k = f & 63, m0 = (f >> 6) * 4;
                uint4v pk = *(const uint4v*)(p0 + k * 64 + m0);
#pragma unroll
                for (int r = 0; r < 4; ++r) {
                    B0h[0][m0 + r][k] = (short)(pk[r] >> 16);
                    B0l[0][m0 + r][k] = (short)(pk[r] & 0xFFFFu);
                }
            }
#pragma unroll
            for (int q = 0; q < 4; ++q) {
                int f = tid + q * 256;
                int n = f >> 4, k0 = (f & 15) * 4;
                float4 vv = *(const float4*)(v0 + n * 64 + k0);
                float va[4] = {vv.x, vv.y, vv.z, vv.w};
                short4v vh4, vl4;
#pragma unroll
                for (int r = 0; r < 4; ++r) { short hh, ll; split_bf16(va[r], hh, ll); vh4[r]=hh; vl4[r]=ll; }
                *(short4v*)&B1h[0][n][k0] = vh4; *(short4v*)&B1l[0][n][k0] = vl4;
            }
        }
        uint4v rP[2][2]; float4 pV[4];
        {
            const unsigned* pc = P32 + (size_t)(base + estride) * 4096;
            const float*    vc = VT  + (size_t)(base + estride) * 4096;
#pragma unroll
            for (int kc = 0; kc < 2; ++kc) {
                const unsigned* p = pc + (size_t)arow*64 + 32*kc + 8*quad;
                rP[kc][0] = *(const uint4v*)p;
                rP[kc][1] = *(const uint4v*)(p + 4);
            }
#pragma unroll
            for (int ni = 0; ni < 4; ++ni)
                pV[ni] = *(const float4*)(vc + (size_t)(l15 + 16*ni)*64 + wr0);
        }
        __syncthreads();

        short8 aH[2], aL[2];
#pragma unroll
        for (int kc = 0; kc < 2; ++kc) unpack_frag(rP[kc][0], rP[kc][1], aH[kc], aL[kc]);

        int cur = 0;
        for (int i = 1; i < 8; ++i) {
            const int idx = base + i * estride;
            floatx4 accP[4], accV[4];
#pragma unroll
            for (int ni = 0; ni < 4; ++ni) {
                accV[ni][0] = pV[ni].x; accV[ni][1] = pV[ni].y;
                accV[ni][2] = pV[ni].z; accV[ni][3] = pV[ni].w;
                accP[ni][0]=accP[ni][1]=accP[ni][2]=accP[ni][3]=0.0f;
            }
            if (i + 1 < 8) {
                const unsigned* pc = P32 + (size_t)(base + (i+1) * estride) * 4096;
                const float*    vc = VT  + (size_t)(base + (i+1) * estride) * 4096;
#pragma unroll
                for (int kc = 0; kc < 2; ++kc) {
                    const unsigned* p = pc + (size_t)arow*64 + 32*kc + 8*quad;
                    rP[kc][0] = *(const uint4v*)p;
                    rP[kc][1] = *(const uint4v*)(p + 4);
                }
#pragma unroll
                for (int ni = 0; ni < 4; ++ni)
                    pV[ni] = *(const float4*)(vc + (size_t)(l15 + 16*ni)*64 + wr0);
            }
#pragma unroll
            for (int kc = 0; kc < 2; ++kc) {
                const int ko = 32*kc + 8*quad;
#pragma unroll
                for (int ni = 0; ni < 4; ++ni) {
                    const int n = l15 + 16*ni;
                    short8 pH = *(const short8*)&B0h[cur][n][ko];
                    short8 pL = *(const short8*)&B0l[cur][n][ko];
                    short8 vH = *(const short8*)&B1h[cur][n][ko];
                    short8 vL = *(const short8*)&B1l[cur][n][ko];
                    accP[ni] = mfma_bf16(aH[kc], pH, accP[ni]);
                    accP[ni] = mfma_bf16(aH[kc], pL, accP[ni]);
                    accP[ni] = mfma_bf16(aL[kc], pH, accP[ni]);
                    accV[ni] = mfma_bf16(aH[kc], vH, accV[ni]);
                    accV[ni] = mfma_bf16(aH[kc], vL, accV[ni]);
                    accV[ni] = mfma_bf16(aL[kc], vH, accV[ni]);
                }
            }
            if (i + 1 < 8) {
#pragma unroll
                for (int kc = 0; kc < 2; ++kc) unpack_frag(rP[kc][0], rP[kc][1], aH[kc], aL[kc]);
            }
            unsigned* po = P32 + (size_t)idx * 4096;
            const int nb = cur ^ 1;
#pragma unroll
            for (int ni = 0; ni < 4; ++ni) {
                const int cc = l15 + 16*ni;
                *(floatx4*)(VT + (size_t)idx*4096 + cc*64 + wr0) = accV[ni];
                short4v h4, l4;
#pragma unroll
                for (int r = 0; r < 4; ++r) {
                    short hh, ll; split_bf16(accP[ni][r], hh, ll);
                    po[(size_t)(wr0+r)*64 + cc] = ((unsigned)(unsigned short)hh << 16) | (unsigned)(unsigned short)ll;
                    h4[r]=hh; l4[r]=ll;
                }
                if (i + 1 < 8) {
                    *(short4v*)&B0h[nb][cc][wr0] = h4; *(short4v*)&B0l[nb][cc][wr0] = l4;
                    short4v vh4, vl4;
#pragma unroll
                    for (int r = 0; r < 4; ++r) { short hh,ll; split_bf16(accV[ni][r],hh,ll); vh4[r]=hh; vl4[r]=ll; }
                    *(short4v*)&B1h[nb][cc][wr0] = vh4; *(short4v*)&B1l[nb][cc][wr0] = vl4;
                }
            }
            if (i + 1 < 8) __syncthreads();
            cur ^= 1;
        }
    };

    if (c < 64) scan8(c * 8, 1);          // L1: in-group prefixes
    grid_barrier(gbar + 1, CN);
    if (c < 8) scan8(64 * c + 7, 8);      // L2: in-super prefixes over group aggs
    grid_barrier(gbar + 2, CN);

    // ---- s3 (block 0): E_{s+1} = P[64s+63]*E_s + V[64s+63] -> dead P32 slots
    if (c == 0) {
#pragma unroll
        for (int q = 0; q < 16; ++q) {
            int f = tid + q * 256; B0h[0][f >> 6][f & 63] = 0; B0l[0][f >> 6][f & 63] = 0;
        }
        uint4v rP[2][2]; float4 pV[4];
        {
            const unsigned* pc = P32 + (size_t)63 * 4096;
            const float*    vc = VT  + (size_t)63 * 4096;
#pragma unroll
            for (int kc = 0; kc < 2; ++kc) {
                const unsigned* p = pc + (size_t)arow*64 + 32*kc + 8*quad;
                rP[kc][0] = *(const uint4v*)p;
                rP[kc][1] = *(const uint4v*)(p + 4);
            }
#pragma unroll
            for (int ni = 0; ni < 4; ++ni)
                pV[ni] = *(const float4*)(vc + (size_t)(l15 + 16*ni)*64 + wr0);
        }
        __syncthreads();

        short8 aH[2], aL[2];
#pragma unroll
        for (int kc = 0; kc < 2; ++kc) unpack_frag(rP[kc][0], rP[kc][1], aH[kc], aL[kc]);

        int cur = 0;
        for (int s = 0; s < 7; ++s) {
            const int idx = 64 * s + 63;
            floatx4 acc[4];
#pragma unroll
            for (int ni = 0; ni < 4; ++ni) {
                acc[ni][0] = pV[ni].x; acc[ni][1] = pV[ni].y;
                acc[ni][2] = pV[ni].z; acc[ni][3] = pV[ni].w;
            }
            if (s + 1 < 7) {
                const int idx2 = 64 * (s + 1) + 63;
                const unsigned* pc = P32 + (size_t)idx2 * 4096;
                const float*    vc = VT  + (size_t)idx2 * 4096;
#pragma unroll
                for (int kc = 0; kc < 2; ++kc) {
                    const unsigned* p = pc + (size_t)arow*64 + 32*kc + 8*quad;
                    rP[kc][0] = *(const uint4v*)p;
                    rP[kc][1] = *(const uint4v*)(p + 4);
                }
#pragma unroll
                for (int ni = 0; ni < 4; ++ni)
                    pV[ni] = *(const float4*)(vc + (size_t)(l15 + 16*ni)*64 + wr0);
            }
#pragma unroll
            for (int kc = 0; kc < 2; ++kc) {
                const int ko = 32*kc + 8*quad;
#pragma unroll
                for (int ni = 0; ni < 4; ++ni) {
                    const int n = l15 + 16*ni;
                    short8 eH = *(const short8*)&B0h[cur][n][ko];
                    short8 eL = *(const short8*)&B0l[cur][n][ko];
                    acc[ni] = mfma_bf16(aH[kc], eH, acc[ni]);
                    acc[ni] = mfma_bf16(aH[kc], eL, acc[ni]);
                    acc[ni] = mfma_bf16(aL[kc], eH, acc[ni]);
                }
            }
            if (s + 1 < 7) {
#pragma unroll
                for (int kc = 0; kc < 2; ++kc) unpack_frag(rP[kc][0], rP[kc][1], aH[kc], aL[kc]);
            }
            float* eo = (float*)(P32 + (size_t)idx * 4096);
            const int nb = cur ^ 1;
#pragma unroll
            for (int ni = 0; ni < 4; ++ni) {
                const int cc = l15 + 16*ni;
                *(floatx4*)(eo + cc*64 + wr0) = acc[ni];
                if (s + 1 < 7) {
                    short4v h4, l4;
#pragma unroll
                    for (int r = 0; r < 4; ++r) { short hh,ll; split_bf16(acc[ni][r],hh,ll); h4[r]=hh; l4[r]=ll; }
                    *(short4v*)&B0h[nb][cc][wr0] = h4; *(short4v*)&B0l[nb][cc][wr0] = l4;
                }
            }
            if (s + 1 < 7) __syncthreads();
            cur ^= 1;
        }
    }
    grid_barrier(gbar + 3, CN);

    // ======================= PHASE 3 =======================
    {
        const int sup = c >> 6, g = c >> 3, gi = g & 7, j = c & 7;

        if (sup == 0) {
#pragma unroll
            for (int q = 0; q < 16; ++q) { int f = tid + q*256; B0h[0][f>>6][f&63] = 0; B0l[0][f>>6][f&63] = 0; }
        } else {
            const float* e = (const float*)(P32 + (size_t)(64*(sup-1) + 63) * 4096);  // E_sup [b][n]
#pragma unroll
            for (int q = 0; q < 4; ++q) {
                int f = tid + q*256; int b = f>>4, k0 = (f&15)*4;
                float4 v = *(const float4*)(e + b*64 + k0);
                float va[4] = {v.x,v.y,v.z,v.w};
                short4v h4, l4;
#pragma unroll
                for (int r=0;r<4;++r){short hh,ll;split_bf16(va[r],hh,ll);h4[r]=hh;l4[r]=ll;}
                *(short4v*)&B0h[0][b][k0] = h4; *(short4v*)&B0l[0][b][k0] = l4;
            }
        }
        __syncthreads();
        int cur = 0;

        auto combine = [&](int idx) {
            uint4v rP[2][2];
            const unsigned* pc = P32 + (size_t)idx * 4096;
            const float*    vc = VT  + (size_t)idx * 4096;
#pragma unroll
            for (int kc = 0; kc < 2; ++kc) {
                const unsigned* p = pc + (size_t)arow*64 + 32*kc + 8*quad;
                rP[kc][0] = *(const uint4v*)p;
                rP[kc][1] = *(const uint4v*)(p + 4);
            }
            floatx4 acc[4];
#pragma unroll
            for (int ni = 0; ni < 4; ++ni) {
                float4 vv = *(const float4*)(vc + (size_t)(l15 + 16*ni)*64 + wr0);
                acc[ni][0]=vv.x; acc[ni][1]=vv.y; acc[ni][2]=vv.z; acc[ni][3]=vv.w;
            }
            short8 cH[2], cL[2];
#pragma unroll
            for (int kc = 0; kc < 2; ++kc) unpack_frag(rP[kc][0], rP[kc][1], cH[kc], cL[kc]);
#pragma unroll
            for (int kc = 0; kc < 2; ++kc) {
                const int ko = 32*kc + 8*quad;
#pragma unroll
                for (int ni = 0; ni < 4; ++ni) {
                    const int n = l15 + 16*ni;
                    short8 xH = *(const short8*)&B0h[cur][n][ko];
                    short8 xL = *(const short8*)&B0l[cur][n][ko];
                    acc[ni] = mfma_bf16(cH[kc], xH, acc[ni]);
                    acc[ni] = mfma_bf16(cH[kc], xL, acc[ni]);
                    acc[ni] = mfma_bf16(cL[kc], xH, acc[ni]);
                }
            }
            const int nb = cur ^ 1;
#pragma unroll
            for (int ni = 0; ni < 4; ++ni) {
                const int cc = l15 + 16*ni;
                short4v h4, l4;
#pragma unroll
                for (int r=0;r<4;++r){short hh,ll;split_bf16(acc[ni][r],hh,ll);h4[r]=hh;l4[r]=ll;}
                *(short4v*)&B0h[nb][cc][wr0] = h4; *(short4v*)&B0l[nb][cc][wr0] = l4;
            }
            __syncthreads();
            cur ^= 1;
        };
        if (gi) combine(8*g - 1);   // in-super group prefix (L2 output)
        if (j)  combine(c - 1);     // in-group chunk prefix (L1 output)

        short8 aH[2], aL[2];
#pragma unroll
        for (int kc = 0; kc < 2; ++kc) cvt_frag(rA3[kc][0], rA3[kc][1], aH[kc], aL[kc]);

        float4 rA[2][2];
        float4 bcur = b3, bnxt;
        float icur[4], inxt[4];
#pragma unroll
        for (int ni = 0; ni < 4; ++ni) icur[ni] = i3[ni];

        floatx4 acc[4];
        for (int s = 0; s < CH; ++s) {
            const int t = t0 + s;
            if (s + 1 < CH) {
                const int t1 = t + 1;
#pragma unroll
                for (int kc = 0; kc < 2; ++kc) {
                    const float* p = Ag + (size_t)t1*4096 + (size_t)arow*64 + 32*kc + 8*quad;
                    rA[kc][0] = *(const float4*)p;
                    rA[kc][1] = *(const float4*)(p + 4);
                }
                bnxt = *(const float4*)(Bst + (size_t)t1*64 + wr0);
#pragma unroll
                for (int ni = 0; ni < 4; ++ni) inxt[ni] = inp[(size_t)t1*64 + l15 + 16*ni];
            }
            {
                float bc[4] = {bcur.x,bcur.y,bcur.z,bcur.w};
#pragma unroll
                for (int ni=0;ni<4;++ni)
#pragma unroll
                for (int r=0;r<4;++r) acc[ni][r] = bc[r] * icur[ni];
            }
#pragma unroll
            for (int kc = 0; kc < 2; ++kc) {
                const int ko = 32*kc + 8*quad;
#pragma unroll
                for (int ni = 0; ni < 4; ++ni) {
                    const int n = l15 + 16*ni;
                    short8 xH = *(const short8*)&B0h[cur][n][ko];
                    short8 xL = *(const short8*)&B0l[cur][n][ko];
                    acc[ni] = mfma_bf16(aH[kc], xH, acc[ni]);
                    acc[ni] = mfma_bf16(aH[kc], xL, acc[ni]);
                    acc[ni] = mfma_bf16(aL[kc], xH, acc[ni]);
                }
            }
            if (s + 1 < CH) {
#pragma unroll
                for (int kc = 0; kc < 2; ++kc) cvt_frag(rA[kc][0], rA[kc][1], aH[kc], aL[kc]);
            }
            const int nb = cur ^ 1;
#pragma unroll
            for (int ni = 0; ni < 4; ++ni) {
                const int cc = l15 + 16*ni;
                *(floatx4*)(out + (size_t)t*4096 + cc*64 + wr0) = acc[ni];   // out[t][b][n0..3]
                if (s + 1 < CH) {
                    short4v h4, l4;
#pragma unroll
                    for (int r=0;r<4;++r){short hh,ll;split_bf16(acc[ni][r],hh,ll);h4[r]=hh;l4[r]=ll;}
                    *(short4v*)&B0h[nb][cc][wr0] = h4; *(short4v*)&B0l[nb][cc][wr0] = l4;
                }
            }
            if (s + 1 < CH) { __syncthreads(); cur ^= 1; }
            bcur = bnxt;
#pragma unroll
            for (int ni = 0; ni < 4; ++ni) icur[ni] = inxt[ni];
        }
    }
}

extern "C" void kernel_launch(void* const* d_in, const int* in_sizes, int n_in,
                              void* d_out, int out_size, void* d_ws, size_t ws_size,
                              hipStream_t stream)
{
    const float* inp = (const float*)d_in[0];   // (L, B)
    const float* A   = (const float*)d_in[1];   // (L, N, N)
    const float* Bst = (const float*)d_in[2];   // (L, N)
    float* out = (float*)d_out;                  // (L, B, N)
    float* ws  = (float*)d_ws;

    unsigned* P32 = (unsigned*)ws;                   // 8 MB: packed hi|lo, row-major
    float*    VT  = (float*)ws + (size_t)CN * 4096;  // 8 MB: fp32, transposed
    unsigned* gbar = (unsigned*)((char*)d_ws + (size_t)16 * 1024 * 1024);  // 4 arrive counters

    hipMemsetAsync(gbar, 0, 4 * sizeof(unsigned), stream);
    hippo_fused<<<CN, 256, 0, stream>>>(inp, A, Bst, P32, VT, out, gbar);
}

// Round 8
// 301.739 us; speedup vs baseline: 2.4130x; 2.4130x over previous
//
#include <hip/hip_runtime.h>
#include <hip/hip_bf16.h>

// L=4096, N=B=64. CH=8 -> CN=512 chunks (2 WG/CU on 256 CUs, exactly resident).
// Scan hierarchy: 512 chunks = 64 groups x 8 = 8 supers x 8 groups x 8.
// P stored ROW-MAJOR packed (hi<<16)|lo bf16 u32; V stored fp32 transposed.
// Wave tiling 16x64 (wave-exclusive A rows, no dup). State dbuf in LDS.
// ONE plain kernel (graph-capturable) + manual grid barrier.
// R8 fix: barrier does ONE wbL2 (release add) + RELAXED polling (no cache
// maintenance per poll!) + ONE L2-inv (final acquire load) per block.
// R7's acquire-per-poll spin emitted buffer_inv every iteration -> 97% idle.
#define TL 4096
#define NB 64
#define CH 8
#define CN 512
#define AS 72          // LDS row stride (bf16): 144 B (odd 16B groups -> conflict-free b128)

typedef __attribute__((ext_vector_type(8))) short short8;
typedef __attribute__((ext_vector_type(4))) short short4v;
typedef __attribute__((ext_vector_type(4))) float floatx4;
typedef __attribute__((ext_vector_type(4))) unsigned int uint4v;

__device__ inline floatx4 mfma_bf16(short8 a, short8 b, floatx4 c) {
    return __builtin_amdgcn_mfma_f32_16x16x32_bf16(a, b, c, 0, 0, 0);
}
__device__ inline short bf16_rne(float x) {
    union { __hip_bfloat16 b; unsigned short s; } u;
    u.b = __float2bfloat16(x);
    return (short)u.s;
}
// fp32 -> (hi, lo) bf16 pair. x ~= hi + lo to ~2^-17 rel.
__device__ inline void split_bf16(float x, short& h, short& l) {
    h = bf16_rne(x);
    union { unsigned u; float f; } hv; hv.u = ((unsigned)(unsigned short)h) << 16;
    l = bf16_rne(x - hv.f);
}
// 8 consecutive fp32 (2 float4) -> hi/lo bf16 fragments
__device__ inline void cvt_frag(float4 a, float4 b, short8& H, short8& L) {
    float v[8] = {a.x,a.y,a.z,a.w,b.x,b.y,b.z,b.w};
#pragma unroll
    for (int r = 0; r < 8; ++r) { short hh,ll; split_bf16(v[r],hh,ll); H[r]=hh; L[r]=ll; }
}
// 8 packed u32 (2 uint4) -> hi/lo fragments
__device__ inline void unpack_frag(uint4v a, uint4v b, short8& H, short8& L) {
#pragma unroll
    for (int r = 0; r < 4; ++r) {
        H[r]   = (short)(a[r] >> 16); L[r]   = (short)(a[r] & 0xFFFFu);
        H[4+r] = (short)(b[r] >> 16); L[4+r] = (short)(b[r] & 0xFFFFu);
    }
}

// Single-use grid barrier (counter pre-zeroed per launch via hipMemsetAsync).
// __syncthreads() drains all waves' vmcnt (compiler emits waitcnt before
// s_barrier), so this block's plain stores are in its XCD L2. The RELEASE
// fetch_add writes that L2 back (one buffer_wbl2); the spin uses RELAXED
// loads (coherent-point read, NO invalidate); the final ACQUIRE load emits
// one buffer_inv so later plain reads see other XCDs' data via L3.
__device__ inline void grid_barrier(unsigned* cnt, unsigned nb) {
    __syncthreads();
    if (threadIdx.x == 0) {
        __hip_atomic_fetch_add(cnt, 1u, __ATOMIC_RELEASE, __HIP_MEMORY_SCOPE_AGENT);
        unsigned v;
        do {
            __builtin_amdgcn_s_sleep(8);
            v = __hip_atomic_load(cnt, __ATOMIC_RELAXED, __HIP_MEMORY_SCOPE_AGENT);
        } while (v < nb);
        (void)__hip_atomic_load(cnt, __ATOMIC_ACQUIRE, __HIP_MEMORY_SCOPE_AGENT);
    }
    __syncthreads();
}

__global__ __launch_bounds__(256, 2)
void hippo_fused(const float* __restrict__ inp, const float* __restrict__ Ag,
                 const float* __restrict__ Bst, unsigned* __restrict__ P32,
                 float* __restrict__ VT, float* __restrict__ out,
                 unsigned* __restrict__ gbar)
{
    // B0: S (phase1) / Pacc (scan) / E (s3) / X (phase3).  B1: V / Vacc.
    __shared__ short B0h[2][NB][AS], B0l[2][NB][AS];
    __shared__ short B1h[2][NB][AS], B1l[2][NB][AS];

    const int tid = threadIdx.x;
    const int c = blockIdx.x, t0 = c * CH;
    const int w = tid >> 6, lane = tid & 63;
    const int quad = lane >> 4, l15 = lane & 15;
    const int arow = 16*w + l15;     // wave-exclusive A/P row
    const int wr0  = 16*w + 4*quad;  // acc row base

    // ======================= PHASE 1 =======================
    {
        float4 rA[2][2];
#pragma unroll
        for (int kc = 0; kc < 2; ++kc) {
            const float* p = Ag + (size_t)(t0+1)*4096 + (size_t)arow*64 + 32*kc + 8*quad;
            rA[kc][0] = *(const float4*)p;
            rA[kc][1] = *(const float4*)(p + 4);
        }
        float4 bnxt = *(const float4*)(Bst + (size_t)(t0+1)*64 + wr0);
        float inxt[4];
#pragma unroll
        for (int ni = 0; ni < 4; ++ni) inxt[ni] = inp[(size_t)(t0+1)*64 + l15 + 16*ni];

        floatx4 accS[4], accV[4];
        {
            const float* A0 = Ag + (size_t)t0 * 4096;
            float4 b0 = *(const float4*)(Bst + (size_t)t0*64 + wr0);
            float bc[4] = {b0.x,b0.y,b0.z,b0.w};
#pragma unroll
            for (int ni = 0; ni < 4; ++ni) {
                const float ii = inp[(size_t)t0*64 + l15 + 16*ni];
#pragma unroll
                for (int r = 0; r < 4; ++r) {
                    accS[ni][r] = A0[(size_t)(wr0 + r)*64 + l15 + 16*ni];
                    accV[ni][r] = bc[r] * ii;
                }
            }
        }
#pragma unroll
        for (int ni = 0; ni < 4; ++ni) {
            const int cc = l15 + 16*ni;
            short4v h4, l4;
#pragma unroll
            for (int r = 0; r < 4; ++r) { short hh,ll; split_bf16(accS[ni][r],hh,ll); h4[r]=hh; l4[r]=ll; }
            *(short4v*)&B0h[0][cc][wr0] = h4; *(short4v*)&B0l[0][cc][wr0] = l4;
#pragma unroll
            for (int r = 0; r < 4; ++r) { short hh,ll; split_bf16(accV[ni][r],hh,ll); h4[r]=hh; l4[r]=ll; }
            *(short4v*)&B1h[0][cc][wr0] = h4; *(short4v*)&B1l[0][cc][wr0] = l4;
        }
        __syncthreads();

        short8 aH[2], aL[2];
#pragma unroll
        for (int kc = 0; kc < 2; ++kc) cvt_frag(rA[kc][0], rA[kc][1], aH[kc], aL[kc]);

        int cur = 0;
        float4 bcur = bnxt;
        float icur[4];
#pragma unroll
        for (int ni = 0; ni < 4; ++ni) icur[ni] = inxt[ni];

        for (int s = 1; s < CH; ++s) {
            if (s + 1 < CH) {
                const int t1 = t0 + s + 1;
#pragma unroll
                for (int kc = 0; kc < 2; ++kc) {
                    const float* p = Ag + (size_t)t1*4096 + (size_t)arow*64 + 32*kc + 8*quad;
                    rA[kc][0] = *(const float4*)p;
                    rA[kc][1] = *(const float4*)(p + 4);
                }
                bnxt = *(const float4*)(Bst + (size_t)t1*64 + wr0);
#pragma unroll
                for (int ni = 0; ni < 4; ++ni) inxt[ni] = inp[(size_t)t1*64 + l15 + 16*ni];
            }
            {
                float bc[4] = {bcur.x,bcur.y,bcur.z,bcur.w};
#pragma unroll
                for (int ni = 0; ni < 4; ++ni)
#pragma unroll
                for (int r = 0; r < 4; ++r) {
                    accS[ni][r] = 0.0f;
                    accV[ni][r] = bc[r] * icur[ni];
                }
            }
#pragma unroll
            for (int kc = 0; kc < 2; ++kc) {
                const int ko = 32*kc + 8*quad;
#pragma unroll
                for (int ni = 0; ni < 4; ++ni) {
                    const int n = l15 + 16*ni;
                    short8 sH = *(const short8*)&B0h[cur][n][ko];
                    short8 sL = *(const short8*)&B0l[cur][n][ko];
                    short8 vH = *(const short8*)&B1h[cur][n][ko];
                    short8 vL = *(const short8*)&B1l[cur][n][ko];
                    accS[ni] = mfma_bf16(aH[kc], sH, accS[ni]);
                    accS[ni] = mfma_bf16(aH[kc], sL, accS[ni]);
                    accS[ni] = mfma_bf16(aL[kc], sH, accS[ni]);
                    accV[ni] = mfma_bf16(aH[kc], vH, accV[ni]);
                    accV[ni] = mfma_bf16(aH[kc], vL, accV[ni]);
                    accV[ni] = mfma_bf16(aL[kc], vH, accV[ni]);
                }
            }
            if (s + 1 < CH) {
#pragma unroll
                for (int kc = 0; kc < 2; ++kc) cvt_frag(rA[kc][0], rA[kc][1], aH[kc], aL[kc]);
                const int nb = cur ^ 1;
#pragma unroll
                for (int ni = 0; ni < 4; ++ni) {
                    const int cc = l15 + 16*ni;
                    short4v h4, l4;
#pragma unroll
                    for (int r = 0; r < 4; ++r) { short hh,ll; split_bf16(accS[ni][r],hh,ll); h4[r]=hh; l4[r]=ll; }
                    *(short4v*)&B0h[nb][cc][wr0] = h4; *(short4v*)&B0l[nb][cc][wr0] = l4;
#pragma unroll
                    for (int r = 0; r < 4; ++r) { short hh,ll; split_bf16(accV[ni][r],hh,ll); h4[r]=hh; l4[r]=ll; }
                    *(short4v*)&B1h[nb][cc][wr0] = h4; *(short4v*)&B1l[nb][cc][wr0] = l4;
                }
                __syncthreads();
                cur ^= 1;
            }
            bcur = bnxt;
#pragma unroll
            for (int ni = 0; ni < 4; ++ni) icur[ni] = inxt[ni];
        }

        unsigned* po = P32 + (size_t)c * 4096;
#pragma unroll
        for (int ni = 0; ni < 4; ++ni) {
            const int cc = l15 + 16*ni;
            *(floatx4*)(VT + (size_t)c*4096 + cc*64 + wr0) = accV[ni];
#pragma unroll
            for (int r = 0; r < 4; ++r) {
                short hh, ll; split_bf16(accS[ni][r], hh, ll);
                po[(size_t)(wr0 + r)*64 + cc] = ((unsigned)(unsigned short)hh << 16) | (unsigned)(unsigned short)ll;
            }
        }
    }

    // phase-3 t0 operand prefetch: issue BEFORE the scan interlude so HBM
    // latency hides under L1/L2/s3 (blocks are otherwise idle there).
    float4 rA3[2][2];
#pragma unroll
    for (int kc = 0; kc < 2; ++kc) {
        const float* p = Ag + (size_t)t0*4096 + (size_t)arow*64 + 32*kc + 8*quad;
        rA3[kc][0] = *(const float4*)p;
        rA3[kc][1] = *(const float4*)(p + 4);
    }
    float4 b3 = *(const float4*)(Bst + (size_t)t0*64 + wr0);
    float i3[4];
#pragma unroll
    for (int ni = 0; ni < 4; ++ni) i3[ni] = inp[(size_t)t0*64 + l15 + 16*ni];

    grid_barrier(gbar + 0, CN);

    // ======================= SCANS =======================
    auto scan8 = [&](int base, int estride) {
        {   // element 0 -> buf 0 (transpose scatter for P, row copy for V)
            const unsigned* p0 = P32 + (size_t)base * 4096;
            const float*    v0 = VT  + (size_t)base * 4096;
#pragma unroll
            for (int q = 0; q < 4; ++q) {
                int f = tid + q * 256;
                int k = f & 63, m0 = (f >> 6) * 4;
                uint4v pk = *(const uint4v*)(p0 + k * 64 + m0);
#pragma unroll
                for (int r = 0; r < 4; ++r) {
                    B0h[0][m0 + r][k] = (short)(pk[r] >> 16);
                    B0l[0][m0 + r][k] = (short)(pk[r] & 0xFFFFu);
                }
            }
#pragma unroll
            for (int q = 0; q < 4; ++q) {
                int f = tid + q * 256;
                int n = f >> 4, k0 = (f & 15) * 4;
                float4 vv = *(const float4*)(v0 + n * 64 + k0);
                float va[4] = {vv.x, vv.y, vv.z, vv.w};
                short4v vh4, vl4;
#pragma unroll
                for (int r = 0; r < 4; ++r) { short hh, ll; split_bf16(va[r], hh, ll); vh4[r]=hh; vl4[r]=ll; }
                *(short4v*)&B1h[0][n][k0] = vh4; *(short4v*)&B1l[0][n][k0] = vl4;
            }
        }
        uint4v rP[2][2]; float4 pV[4];
        {
            const unsigned* pc = P32 + (size_t)(base + estride) * 4096;
            const float*    vc = VT  + (size_t)(base + estride) * 4096;
#pragma unroll
            for (int kc = 0; kc < 2; ++kc) {
                const unsigned* p = pc + (size_t)arow*64 + 32*kc + 8*quad;
                rP[kc][0] = *(const uint4v*)p;
                rP[kc][1] = *(const uint4v*)(p + 4);
            }
#pragma unroll
            for (int ni = 0; ni < 4; ++ni)
                pV[ni] = *(const float4*)(vc + (size_t)(l15 + 16*ni)*64 + wr0);
        }
        __syncthreads();

        short8 aH[2], aL[2];
#pragma unroll
        for (int kc = 0; kc < 2; ++kc) unpack_frag(rP[kc][0], rP[kc][1], aH[kc], aL[kc]);

        int cur = 0;
        for (int i = 1; i < 8; ++i) {
            const int idx = base + i * estride;
            floatx4 accP[4], accV[4];
#pragma unroll
            for (int ni = 0; ni < 4; ++ni) {
                accV[ni][0] = pV[ni].x; accV[ni][1] = pV[ni].y;
                accV[ni][2] = pV[ni].z; accV[ni][3] = pV[ni].w;
                accP[ni][0]=accP[ni][1]=accP[ni][2]=accP[ni][3]=0.0f;
            }
            if (i + 1 < 8) {
                const unsigned* pc = P32 + (size_t)(base + (i+1) * estride) * 4096;
                const float*    vc = VT  + (size_t)(base + (i+1) * estride) * 4096;
#pragma unroll
                for (int kc = 0; kc < 2; ++kc) {
                    const unsigned* p = pc + (size_t)arow*64 + 32*kc + 8*quad;
                    rP[kc][0] = *(const uint4v*)p;
                    rP[kc][1] = *(const uint4v*)(p + 4);
                }
#pragma unroll
                for (int ni = 0; ni < 4; ++ni)
                    pV[ni] = *(const float4*)(vc + (size_t)(l15 + 16*ni)*64 + wr0);
            }
#pragma unroll
            for (int kc = 0; kc < 2; ++kc) {
                const int ko = 32*kc + 8*quad;
#pragma unroll
                for (int ni = 0; ni < 4; ++ni) {
                    const int n = l15 + 16*ni;
                    short8 pH = *(const short8*)&B0h[cur][n][ko];
                    short8 pL = *(const short8*)&B0l[cur][n][ko];
                    short8 vH = *(const short8*)&B1h[cur][n][ko];
                    short8 vL = *(const short8*)&B1l[cur][n][ko];
                    accP[ni] = mfma_bf16(aH[kc], pH, accP[ni]);
                    accP[ni] = mfma_bf16(aH[kc], pL, accP[ni]);
                    accP[ni] = mfma_bf16(aL[kc], pH, accP[ni]);
                    accV[ni] = mfma_bf16(aH[kc], vH, accV[ni]);
                    accV[ni] = mfma_bf16(aH[kc], vL, accV[ni]);
                    accV[ni] = mfma_bf16(aL[kc], vH, accV[ni]);
                }
            }
            if (i + 1 < 8) {
#pragma unroll
                for (int kc = 0; kc < 2; ++kc) unpack_frag(rP[kc][0], rP[kc][1], aH[kc], aL[kc]);
            }
            unsigned* po = P32 + (size_t)idx * 4096;
            const int nb = cur ^ 1;
#pragma unroll
            for (int ni = 0; ni < 4; ++ni) {
                const int cc = l15 + 16*ni;
                *(floatx4*)(VT + (size_t)idx*4096 + cc*64 + wr0) = accV[ni];
                short4v h4, l4;
#pragma unroll
                for (int r = 0; r < 4; ++r) {
                    short hh, ll; split_bf16(accP[ni][r], hh, ll);
                    po[(size_t)(wr0+r)*64 + cc] = ((unsigned)(unsigned short)hh << 16) | (unsigned)(unsigned short)ll;
                    h4[r]=hh; l4[r]=ll;
                }
                if (i + 1 < 8) {
                    *(short4v*)&B0h[nb][cc][wr0] = h4; *(short4v*)&B0l[nb][cc][wr0] = l4;
                    short4v vh4, vl4;
#pragma unroll
                    for (int r = 0; r < 4; ++r) { short hh,ll; split_bf16(accV[ni][r],hh,ll); vh4[r]=hh; vl4[r]=ll; }
                    *(short4v*)&B1h[nb][cc][wr0] = vh4; *(short4v*)&B1l[nb][cc][wr0] = vl4;
                }
            }
            if (i + 1 < 8) __syncthreads();
            cur ^= 1;
        }
    };

    if (c < 64) scan8(c * 8, 1);          // L1: in-group prefixes
    grid_barrier(gbar + 1, CN);
    if (c < 8) scan8(64 * c + 7, 8);      // L2: in-super prefixes over group aggs
    grid_barrier(gbar + 2, CN);

    // ---- s3 (block 0): E_{s+1} = P[64s+63]*E_s + V[64s+63] -> dead P32 slots
    if (c == 0) {
#pragma unroll
        for (int q = 0; q < 16; ++q) {
            int f = tid + q * 256; B0h[0][f >> 6][f & 63] = 0; B0l[0][f >> 6][f & 63] = 0;
        }
        uint4v rP[2][2]; float4 pV[4];
        {
            const unsigned* pc = P32 + (size_t)63 * 4096;
            const float*    vc = VT  + (size_t)63 * 4096;
#pragma unroll
            for (int kc = 0; kc < 2; ++kc) {
                const unsigned* p = pc + (size_t)arow*64 + 32*kc + 8*quad;
                rP[kc][0] = *(const uint4v*)p;
                rP[kc][1] = *(const uint4v*)(p + 4);
            }
#pragma unroll
            for (int ni = 0; ni < 4; ++ni)
                pV[ni] = *(const float4*)(vc + (size_t)(l15 + 16*ni)*64 + wr0);
        }
        __syncthreads();

        short8 aH[2], aL[2];
#pragma unroll
        for (int kc = 0; kc < 2; ++kc) unpack_frag(rP[kc][0], rP[kc][1], aH[kc], aL[kc]);

        int cur = 0;
        for (int s = 0; s < 7; ++s) {
            const int idx = 64 * s + 63;
            floatx4 acc[4];
#pragma unroll
            for (int ni = 0; ni < 4; ++ni) {
                acc[ni][0] = pV[ni].x; acc[ni][1] = pV[ni].y;
                acc[ni][2] = pV[ni].z; acc[ni][3] = pV[ni].w;
            }
            if (s + 1 < 7) {
                const int idx2 = 64 * (s + 1) + 63;
                const unsigned* pc = P32 + (size_t)idx2 * 4096;
                const float*    vc = VT  + (size_t)idx2 * 4096;
#pragma unroll
                for (int kc = 0; kc < 2; ++kc) {
                    const unsigned* p = pc + (size_t)arow*64 + 32*kc + 8*quad;
                    rP[kc][0] = *(const uint4v*)p;
                    rP[kc][1] = *(const uint4v*)(p + 4);
                }
#pragma unroll
                for (int ni = 0; ni < 4; ++ni)
                    pV[ni] = *(const float4*)(vc + (size_t)(l15 + 16*ni)*64 + wr0);
            }
#pragma unroll
            for (int kc = 0; kc < 2; ++kc) {
                const int ko = 32*kc + 8*quad;
#pragma unroll
                for (int ni = 0; ni < 4; ++ni) {
                    const int n = l15 + 16*ni;
                    short8 eH = *(const short8*)&B0h[cur][n][ko];
                    short8 eL = *(const short8*)&B0l[cur][n][ko];
                    acc[ni] = mfma_bf16(aH[kc], eH, acc[ni]);
                    acc[ni] = mfma_bf16(aH[kc], eL, acc[ni]);
                    acc[ni] = mfma_bf16(aL[kc], eH, acc[ni]);
                }
            }
            if (s + 1 < 7) {
#pragma unroll
                for (int kc = 0; kc < 2; ++kc) unpack_frag(rP[kc][0], rP[kc][1], aH[kc], aL[kc]);
            }
            float* eo = (float*)(P32 + (size_t)idx * 4096);
            const int nb = cur ^ 1;
#pragma unroll
            for (int ni = 0; ni < 4; ++ni) {
                const int cc = l15 + 16*ni;
                *(floatx4*)(eo + cc*64 + wr0) = acc[ni];
                if (s + 1 < 7) {
                    short4v h4, l4;
#pragma unroll
                    for (int r = 0; r < 4; ++r) { short hh,ll; split_bf16(acc[ni][r],hh,ll); h4[r]=hh; l4[r]=ll; }
                    *(short4v*)&B0h[nb][cc][wr0] = h4; *(short4v*)&B0l[nb][cc][wr0] = l4;
                }
            }
            if (s + 1 < 7) __syncthreads();
            cur ^= 1;
        }
    }
    grid_barrier(gbar + 3, CN);

    // ======================= PHASE 3 =======================
    {
        const int sup = c >> 6, g = c >> 3, gi = g & 7, j = c & 7;

        if (sup == 0) {
#pragma unroll
            for (int q = 0; q < 16; ++q) { int f = tid + q*256; B0h[0][f>>6][f&63] = 0; B0l[0][f>>6][f&63] = 0; }
        } else {
            const float* e = (const float*)(P32 + (size_t)(64*(sup-1) + 63) * 4096);  // E_sup [b][n]
#pragma unroll
            for (int q = 0; q < 4; ++q) {
                int f = tid + q*256; int b = f>>4, k0 = (f&15)*4;
                float4 v = *(const float4*)(e + b*64 + k0);
                float va[4] = {v.x,v.y,v.z,v.w};
                short4v h4, l4;
#pragma unroll
                for (int r=0;r<4;++r){short hh,ll;split_bf16(va[r],hh,ll);h4[r]=hh;l4[r]=ll;}
                *(short4v*)&B0h[0][b][k0] = h4; *(short4v*)&B0l[0][b][k0] = l4;
            }
        }
        __syncthreads();
        int cur = 0;

        auto combine = [&](int idx) {
            uint4v rP[2][2];
            const unsigned* pc = P32 + (size_t)idx * 4096;
            const float*    vc = VT  + (size_t)idx * 4096;
#pragma unroll
            for (int kc = 0; kc < 2; ++kc) {
                const unsigned* p = pc + (size_t)arow*64 + 32*kc + 8*quad;
                rP[kc][0] = *(const uint4v*)p;
                rP[kc][1] = *(const uint4v*)(p + 4);
            }
            floatx4 acc[4];
#pragma unroll
            for (int ni = 0; ni < 4; ++ni) {
                float4 vv = *(const float4*)(vc + (size_t)(l15 + 16*ni)*64 + wr0);
                acc[ni][0]=vv.x; acc[ni][1]=vv.y; acc[ni][2]=vv.z; acc[ni][3]=vv.w;
            }
            short8 cH[2], cL[2];
#pragma unroll
            for (int kc = 0; kc < 2; ++kc) unpack_frag(rP[kc][0], rP[kc][1], cH[kc], cL[kc]);
#pragma unroll
            for (int kc = 0; kc < 2; ++kc) {
                const int ko = 32*kc + 8*quad;
#pragma unroll
                for (int ni = 0; ni < 4; ++ni) {
                    const int n = l15 + 16*ni;
                    short8 xH = *(const short8*)&B0h[cur][n][ko];
                    short8 xL = *(const short8*)&B0l[cur][n][ko];
                    acc[ni] = mfma_bf16(cH[kc], xH, acc[ni]);
                    acc[ni] = mfma_bf16(cH[kc], xL, acc[ni]);
                    acc[ni] = mfma_bf16(cL[kc], xH, acc[ni]);
                }
            }
            const int nb = cur ^ 1;
#pragma unroll
            for (int ni = 0; ni < 4; ++ni) {
                const int cc = l15 + 16*ni;
                short4v h4, l4;
#pragma unroll
                for (int r=0;r<4;++r){short hh,ll;split_bf16(acc[ni][r],hh,ll);h4[r]=hh;l4[r]=ll;}
                *(short4v*)&B0h[nb][cc][wr0] = h4; *(short4v*)&B0l[nb][cc][wr0] = l4;
            }
            __syncthreads();
            cur ^= 1;
        };
        if (gi) combine(8*g - 1);   // in-super group prefix (L2 output)
        if (j)  combine(c - 1);     // in-group chunk prefix (L1 output)

        short8 aH[2], aL[2];
#pragma unroll
        for (int kc = 0; kc < 2; ++kc) cvt_frag(rA3[kc][0], rA3[kc][1], aH[kc], aL[kc]);

        float4 rA[2][2];
        float4 bcur = b3, bnxt;
        float icur[4], inxt[4];
#pragma unroll
        for (int ni = 0; ni < 4; ++ni) icur[ni] = i3[ni];

        floatx4 acc[4];
        for (int s = 0; s < CH; ++s) {
            const int t = t0 + s;
            if (s + 1 < CH) {
                const int t1 = t + 1;
#pragma unroll
                for (int kc = 0; kc < 2; ++kc) {
                    const float* p = Ag + (size_t)t1*4096 + (size_t)arow*64 + 32*kc + 8*quad;
                    rA[kc][0] = *(const float4*)p;
                    rA[kc][1] = *(const float4*)(p + 4);
                }
                bnxt = *(const float4*)(Bst + (size_t)t1*64 + wr0);
#pragma unroll
                for (int ni = 0; ni < 4; ++ni) inxt[ni] = inp[(size_t)t1*64 + l15 + 16*ni];
            }
            {
                float bc[4] = {bcur.x,bcur.y,bcur.z,bcur.w};
#pragma unroll
                for (int ni=0;ni<4;++ni)
#pragma unroll
                for (int r=0;r<4;++r) acc[ni][r] = bc[r] * icur[ni];
            }
#pragma unroll
            for (int kc = 0; kc < 2; ++kc) {
                const int ko = 32*kc + 8*quad;
#pragma unroll
                for (int ni = 0; ni < 4; ++ni) {
                    const int n = l15 + 16*ni;
                    short8 xH = *(const short8*)&B0h[cur][n][ko];
                    short8 xL = *(const short8*)&B0l[cur][n][ko];
                    acc[ni] = mfma_bf16(aH[kc], xH, acc[ni]);
                    acc[ni] = mfma_bf16(aH[kc], xL, acc[ni]);
                    acc[ni] = mfma_bf16(aL[kc], xH, acc[ni]);
                }
            }
            if (s + 1 < CH) {
#pragma unroll
                for (int kc = 0; kc < 2; ++kc) cvt_frag(rA[kc][0], rA[kc][1], aH[kc], aL[kc]);
            }
            const int nb = cur ^ 1;
#pragma unroll
            for (int ni = 0; ni < 4; ++ni) {
                const int cc = l15 + 16*ni;
                *(floatx4*)(out + (size_t)t*4096 + cc*64 + wr0) = acc[ni];   // out[t][b][n0..3]
                if (s + 1 < CH) {
                    short4v h4, l4;
#pragma unroll
                    for (int r=0;r<4;++r){short hh,ll;split_bf16(acc[ni][r],hh,ll);h4[r]=hh;l4[r]=ll;}
                    *(short4v*)&B0h[nb][cc][wr0] = h4; *(short4v*)&B0l[nb][cc][wr0] = l4;
                }
            }
            if (s + 1 < CH) { __syncthreads(); cur ^= 1; }
            bcur = bnxt;
#pragma unroll
            for (int ni = 0; ni < 4; ++ni) icur[ni] = inxt[ni];
        }
    }
}

extern "C" void kernel_launch(void* const* d_in, const int* in_sizes, int n_in,
                              void* d_out, int out_size, void* d_ws, size_t ws_size,
                              hipStream_t stream)
{
    const float* inp = (const float*)d_in[0];   // (L, B)
    const float* A   = (const float*)d_in[1];   // (L, N, N)
    const float* Bst = (const float*)d_in[2];   // (L, N)
    float* out = (float*)d_out;                  // (L, B, N)
    float* ws  = (float*)d_ws;

    unsigned* P32 = (unsigned*)ws;                   // 8 MB: packed hi|lo, row-major
    float*    VT  = (float*)ws + (size_t)CN * 4096;  // 8 MB: fp32, transposed
    unsigned* gbar = (unsigned*)((char*)d_ws + (size_t)16 * 1024 * 1024);  // 4 arrive counters

    hipMemsetAsync(gbar, 0, 4 * sizeof(unsigned), stream);
    hippo_fused<<<CN, 256, 0, stream>>>(inp, A, Bst, P32, VT, out, gbar);
}

// Round 9
// 187.626 us; speedup vs baseline: 3.8806x; 1.6082x over previous
//
#include <hip/hip_runtime.h>
#include <hip/hip_bf16.h>

// L=4096, N=B=64. CH=8 -> CN=512 chunks (2 WG/CU on 256 CUs).
// Scan hierarchy: 512 chunks = 64 groups x 8 = 8 supers x 8 groups x 8.
// P stored ROW-MAJOR packed (hi<<16)|lo bf16 u32; V stored fp32 transposed.
// Wave tiling 16x64 (wave-exclusive A rows, no dup). State dbuf in LDS,
// one barrier per step.  3 kernels: phase1 | merged-scan | phase3.
// The merged scan (L1 + L2 + s3) uses R8's verified release/relaxed/acquire
// grid barrier with EARLY EXIT: only 64- and 8-block barriers (~72 L2
// wb/inv ops total, vs R7/R8's 2048 which made full fusion net-negative).
#define TL 4096
#define NB 64
#define CH 8
#define CN 512
#define AS 72          // LDS row stride (bf16): 144 B (odd 16B groups -> conflict-free b128)

typedef __attribute__((ext_vector_type(8))) short short8;
typedef __attribute__((ext_vector_type(4))) short short4v;
typedef __attribute__((ext_vector_type(4))) float floatx4;
typedef __attribute__((ext_vector_type(4))) unsigned int uint4v;

__device__ inline floatx4 mfma_bf16(short8 a, short8 b, floatx4 c) {
    return __builtin_amdgcn_mfma_f32_16x16x32_bf16(a, b, c, 0, 0, 0);
}
__device__ inline short bf16_rne(float x) {
    union { __hip_bfloat16 b; unsigned short s; } u;
    u.b = __float2bfloat16(x);
    return (short)u.s;
}
// fp32 -> (hi, lo) bf16 pair. x ~= hi + lo to ~2^-17 rel.
__device__ inline void split_bf16(float x, short& h, short& l) {
    h = bf16_rne(x);
    union { unsigned u; float f; } hv; hv.u = ((unsigned)(unsigned short)h) << 16;
    l = bf16_rne(x - hv.f);
}
// 8 consecutive fp32 (2 float4) -> hi/lo bf16 fragments
__device__ inline void cvt_frag(float4 a, float4 b, short8& H, short8& L) {
    float v[8] = {a.x,a.y,a.z,a.w,b.x,b.y,b.z,b.w};
#pragma unroll
    for (int r = 0; r < 8; ++r) { short hh,ll; split_bf16(v[r],hh,ll); H[r]=hh; L[r]=ll; }
}
// 8 packed u32 (2 uint4) -> hi/lo fragments
__device__ inline void unpack_frag(uint4v a, uint4v b, short8& H, short8& L) {
#pragma unroll
    for (int r = 0; r < 4; ++r) {
        H[r]   = (short)(a[r] >> 16); L[r]   = (short)(a[r] & 0xFFFFu);
        H[4+r] = (short)(b[r] >> 16); L[4+r] = (short)(b[r] & 0xFFFFu);
    }
}

// ---------------------------------------------------------------------------
// Phase 1: per chunk c, S <- A[t]*S (S0=I), V <- A[t]*V + b_t (x) i_t.
// Step 0 direct (S=A[t0] exact). A-frags per-wave from global (no dup);
// state dbuf in LDS, one barrier per step.
// Emits P32[c] = S row-major packed hi|lo, VT[c] = V^T fp32.
// ---------------------------------------------------------------------------
__global__ __launch_bounds__(256, 2)
void hippo_phase1(const float* __restrict__ inp, const float* __restrict__ Ag,
                  const float* __restrict__ Bst,
                  unsigned* __restrict__ P32, float* __restrict__ VT)
{
    __shared__ short SBh[2][NB][AS], SBl[2][NB][AS];
    __shared__ short VBh[2][NB][AS], VBl[2][NB][AS];

    const int tid = threadIdx.x;
    const int c = blockIdx.x, t0 = c * CH;
    const int w = tid >> 6, lane = tid & 63;
    const int quad = lane >> 4, l15 = lane & 15;
    const int arow = 16*w + l15;     // wave-exclusive A row
    const int wr0  = 16*w + 4*quad;  // acc row base

    float4 rA[2][2];
#pragma unroll
    for (int kc = 0; kc < 2; ++kc) {
        const float* p = Ag + (size_t)(t0+1)*4096 + (size_t)arow*64 + 32*kc + 8*quad;
        rA[kc][0] = *(const float4*)p;
        rA[kc][1] = *(const float4*)(p + 4);
    }
    float4 bnxt = *(const float4*)(Bst + (size_t)(t0+1)*64 + wr0);
    float inxt[4];
#pragma unroll
    for (int ni = 0; ni < 4; ++ni) inxt[ni] = inp[(size_t)(t0+1)*64 + l15 + 16*ni];

    // ---- s=0 direct: S = A[t0] (exact fp32), V = b0 (x) i0 ----
    floatx4 accS[4], accV[4];
    {
        const float* A0 = Ag + (size_t)t0 * 4096;
        float4 b0 = *(const float4*)(Bst + (size_t)t0*64 + wr0);
        float bc[4] = {b0.x,b0.y,b0.z,b0.w};
#pragma unroll
        for (int ni = 0; ni < 4; ++ni) {
            const float ii = inp[(size_t)t0*64 + l15 + 16*ni];
#pragma unroll
            for (int r = 0; r < 4; ++r) {
                accS[ni][r] = A0[(size_t)(wr0 + r)*64 + l15 + 16*ni];
                accV[ni][r] = bc[r] * ii;
            }
        }
    }
#pragma unroll
    for (int ni = 0; ni < 4; ++ni) {
        const int cc = l15 + 16*ni;
        short4v h4, l4;
#pragma unroll
        for (int r = 0; r < 4; ++r) { short hh,ll; split_bf16(accS[ni][r],hh,ll); h4[r]=hh; l4[r]=ll; }
        *(short4v*)&SBh[0][cc][wr0] = h4; *(short4v*)&SBl[0][cc][wr0] = l4;
#pragma unroll
        for (int r = 0; r < 4; ++r) { short hh,ll; split_bf16(accV[ni][r],hh,ll); h4[r]=hh; l4[r]=ll; }
        *(short4v*)&VBh[0][cc][wr0] = h4; *(short4v*)&VBl[0][cc][wr0] = l4;
    }
    __syncthreads();

    short8 aH[2], aL[2];
#pragma unroll
    for (int kc = 0; kc < 2; ++kc) cvt_frag(rA[kc][0], rA[kc][1], aH[kc], aL[kc]);

    int cur = 0;
    float4 bcur = bnxt;
    float icur[4];
#pragma unroll
    for (int ni = 0; ni < 4; ++ni) icur[ni] = inxt[ni];

    for (int s = 1; s < CH; ++s) {
        if (s + 1 < CH) {   // prefetch A/b/i for s+1
            const int t1 = t0 + s + 1;
#pragma unroll
            for (int kc = 0; kc < 2; ++kc) {
                const float* p = Ag + (size_t)t1*4096 + (size_t)arow*64 + 32*kc + 8*quad;
                rA[kc][0] = *(const float4*)p;
                rA[kc][1] = *(const float4*)(p + 4);
            }
            bnxt = *(const float4*)(Bst + (size_t)t1*64 + wr0);
#pragma unroll
            for (int ni = 0; ni < 4; ++ni) inxt[ni] = inp[(size_t)t1*64 + l15 + 16*ni];
        }
        {
            float bc[4] = {bcur.x,bcur.y,bcur.z,bcur.w};
#pragma unroll
            for (int ni = 0; ni < 4; ++ni)
#pragma unroll
            for (int r = 0; r < 4; ++r) {
                accS[ni][r] = 0.0f;
                accV[ni][r] = bc[r] * icur[ni];
            }
        }
#pragma unroll
        for (int kc = 0; kc < 2; ++kc) {
            const int ko = 32*kc + 8*quad;
#pragma unroll
            for (int ni = 0; ni < 4; ++ni) {
                const int n = l15 + 16*ni;
                short8 sH = *(const short8*)&SBh[cur][n][ko];
                short8 sL = *(const short8*)&SBl[cur][n][ko];
                short8 vH = *(const short8*)&VBh[cur][n][ko];
                short8 vL = *(const short8*)&VBl[cur][n][ko];
                accS[ni] = mfma_bf16(aH[kc], sH, accS[ni]);
                accS[ni] = mfma_bf16(aH[kc], sL, accS[ni]);
                accS[ni] = mfma_bf16(aL[kc], sH, accS[ni]);
                accV[ni] = mfma_bf16(aH[kc], vH, accV[ni]);
                accV[ni] = mfma_bf16(aH[kc], vL, accV[ni]);
                accV[ni] = mfma_bf16(aL[kc], vH, accV[ni]);
            }
        }
        if (s + 1 < CH) {
#pragma unroll
            for (int kc = 0; kc < 2; ++kc) cvt_frag(rA[kc][0], rA[kc][1], aH[kc], aL[kc]);
            const int nb = cur ^ 1;
#pragma unroll
            for (int ni = 0; ni < 4; ++ni) {
                const int cc = l15 + 16*ni;
                short4v h4, l4;
#pragma unroll
                for (int r = 0; r < 4; ++r) { short hh,ll; split_bf16(accS[ni][r],hh,ll); h4[r]=hh; l4[r]=ll; }
                *(short4v*)&SBh[nb][cc][wr0] = h4; *(short4v*)&SBl[nb][cc][wr0] = l4;
#pragma unroll
                for (int r = 0; r < 4; ++r) { short hh,ll; split_bf16(accV[ni][r],hh,ll); h4[r]=hh; l4[r]=ll; }
                *(short4v*)&VBh[nb][cc][wr0] = h4; *(short4v*)&VBl[nb][cc][wr0] = l4;
            }
            __syncthreads();
            cur ^= 1;
        }
        bcur = bnxt;
#pragma unroll
        for (int ni = 0; ni < 4; ++ni) icur[ni] = inxt[ni];
    }

    unsigned* po = P32 + (size_t)c * 4096;
#pragma unroll
    for (int ni = 0; ni < 4; ++ni) {
        const int cc = l15 + 16*ni;
        *(floatx4*)(VT + (size_t)c*4096 + cc*64 + wr0) = accV[ni];
#pragma unroll
        for (int r = 0; r < 4; ++r) {
            short hh, ll; split_bf16(accS[ni][r], hh, ll);
            po[(size_t)(wr0 + r)*64 + cc] = ((unsigned)(unsigned short)hh << 16) | (unsigned)(unsigned short)ll;
        }
    }
}

// ---------------------------------------------------------------------------
// Merged scan kernel: 64 blocks.
//   all 64 : in-group L1 scan (8 chunks each, in place)
//   barrier(64, early-exit)    [R8-verified release/relaxed/acquire pattern]
//   blocks 0-7 : in-super L2 scan over group aggregates (slots ==7 mod 8)
//   barrier(8, early-exit)
//   block 0 : s3 V-recurrence over super aggregates -> dead P32 slots 64s+63
// ---------------------------------------------------------------------------
__global__ __launch_bounds__(256, 2)
void hippo_scan(unsigned* __restrict__ P32, float* __restrict__ VT,
                unsigned* __restrict__ gbar)
{
    __shared__ short PBh[2][NB][AS], PBl[2][NB][AS];
    __shared__ short VBh[2][NB][AS], VBl[2][NB][AS];

    const int tid = threadIdx.x, c = blockIdx.x;
    const int w = tid >> 6, lane = tid & 63;
    const int quad = lane >> 4, l15 = lane & 15;
    const int arow = 16*w + l15;
    const int wr0  = 16*w + 4*quad;

    // In-place scan of 8 elements: slot i <- inclusive prefix 0..i.
    auto scan8 = [&](int base, int estride) {
        {   // element 0 -> buf 0 (transpose scatter for P, row copy for V)
            const unsigned* p0 = P32 + (size_t)base * 4096;
            const float*    v0 = VT  + (size_t)base * 4096;
#pragma unroll
            for (int q = 0; q < 4; ++q) {
                int f = tid + q * 256;
                int k = f & 63, m0 = (f >> 6) * 4;
                uint4v pk = *(const uint4v*)(p0 + k * 64 + m0);
#pragma unroll
                for (int r = 0; r < 4; ++r) {
                    PBh[0][m0 + r][k] = (short)(pk[r] >> 16);
                    PBl[0][m0 + r][k] = (short)(pk[r] & 0xFFFFu);
                }
            }
#pragma unroll
            for (int q = 0; q < 4; ++q) {
                int f = tid + q * 256;
                int n = f >> 4, k0 = (f & 15) * 4;
                float4 vv = *(const float4*)(v0 + n * 64 + k0);
                float va[4] = {vv.x, vv.y, vv.z, vv.w};
                short4v vh4, vl4;
#pragma unroll
                for (int r = 0; r < 4; ++r) { short hh, ll; split_bf16(va[r], hh, ll); vh4[r]=hh; vl4[r]=ll; }
                *(short4v*)&VBh[0][n][k0] = vh4; *(short4v*)&VBl[0][n][k0] = vl4;
            }
        }
        uint4v rP[2][2]; float4 pV[4];
        {
            const unsigned* pc = P32 + (size_t)(base + estride) * 4096;
            const float*    vc = VT  + (size_t)(base + estride) * 4096;
#pragma unroll
            for (int kc = 0; kc < 2; ++kc) {
                const unsigned* p = pc + (size_t)arow*64 + 32*kc + 8*quad;
                rP[kc][0] = *(const uint4v*)p;
                rP[kc][1] = *(const uint4v*)(p + 4);
            }
#pragma unroll
            for (int ni = 0; ni < 4; ++ni)
                pV[ni] = *(const float4*)(vc + (size_t)(l15 + 16*ni)*64 + wr0);
        }
        __syncthreads();

        short8 aH[2], aL[2];
#pragma unroll
        for (int kc = 0; kc < 2; ++kc) unpack_frag(rP[kc][0], rP[kc][1], aH[kc], aL[kc]);

        int cur = 0;
        for (int i = 1; i < 8; ++i) {
            const int idx = base + i * estride;
            floatx4 accP[4], accV[4];
#pragma unroll
            for (int ni = 0; ni < 4; ++ni) {
                accV[ni][0] = pV[ni].x; accV[ni][1] = pV[ni].y;
                accV[ni][2] = pV[ni].z; accV[ni][3] = pV[ni].w;
                accP[ni][0]=accP[ni][1]=accP[ni][2]=accP[ni][3]=0.0f;
            }
            if (i + 1 < 8) {
                const unsigned* pc = P32 + (size_t)(base + (i+1) * estride) * 4096;
                const float*    vc = VT  + (size_t)(base + (i+1) * estride) * 4096;
#pragma unroll
                for (int kc = 0; kc < 2; ++kc) {
                    const unsigned* p = pc + (size_t)arow*64 + 32*kc + 8*quad;
                    rP[kc][0] = *(const uint4v*)p;
                    rP[kc][1] = *(const uint4v*)(p + 4);
                }
#pragma unroll
                for (int ni = 0; ni < 4; ++ni)
                    pV[ni] = *(const float4*)(vc + (size_t)(l15 + 16*ni)*64 + wr0);
            }
#pragma unroll
            for (int kc = 0; kc < 2; ++kc) {
                const int ko = 32*kc + 8*quad;
#pragma unroll
                for (int ni = 0; ni < 4; ++ni) {
                    const int n = l15 + 16*ni;
                    short8 pH = *(const short8*)&PBh[cur][n][ko];
                    short8 pL = *(const short8*)&PBl[cur][n][ko];
                    short8 vH = *(const short8*)&VBh[cur][n][ko];
                    short8 vL = *(const short8*)&VBl[cur][n][ko];
                    accP[ni] = mfma_bf16(aH[kc], pH, accP[ni]);
                    accP[ni] = mfma_bf16(aH[kc], pL, accP[ni]);
                    accP[ni] = mfma_bf16(aL[kc], pH, accP[ni]);
                    accV[ni] = mfma_bf16(aH[kc], vH, accV[ni]);
                    accV[ni] = mfma_bf16(aH[kc], vL, accV[ni]);
                    accV[ni] = mfma_bf16(aL[kc], vH, accV[ni]);
                }
            }
            if (i + 1 < 8) {
#pragma unroll
                for (int kc = 0; kc < 2; ++kc) unpack_frag(rP[kc][0], rP[kc][1], aH[kc], aL[kc]);
            }
            unsigned* po = P32 + (size_t)idx * 4096;
            const int nb = cur ^ 1;
#pragma unroll
            for (int ni = 0; ni < 4; ++ni) {
                const int cc = l15 + 16*ni;
                *(floatx4*)(VT + (size_t)idx*4096 + cc*64 + wr0) = accV[ni];
                short4v h4, l4;
#pragma unroll
                for (int r = 0; r < 4; ++r) {
                    short hh, ll; split_bf16(accP[ni][r], hh, ll);
                    po[(size_t)(wr0+r)*64 + cc] = ((unsigned)(unsigned short)hh << 16) | (unsigned)(unsigned short)ll;
                    h4[r]=hh; l4[r]=ll;
                }
                if (i + 1 < 8) {
                    *(short4v*)&PBh[nb][cc][wr0] = h4; *(short4v*)&PBl[nb][cc][wr0] = l4;
                    short4v vh4, vl4;
#pragma unroll
                    for (int r = 0; r < 4; ++r) { short hh,ll; split_bf16(accV[ni][r],hh,ll); vh4[r]=hh; vl4[r]=ll; }
                    *(short4v*)&VBh[nb][cc][wr0] = vh4; *(short4v*)&VBl[nb][cc][wr0] = vl4;
                }
            }
            if (i + 1 < 8) __syncthreads();
            cur ^= 1;
        }
    };

    // ---- L1: all 64 blocks scan their group ----
    scan8(c * 8, 1);

    // barrier(64) with early exit: every block release-arrives (one L2 wb);
    // only blocks 0-7 poll (relaxed, no cache traffic) + one acquire inv.
    __syncthreads();
    if (tid == 0)
        __hip_atomic_fetch_add(gbar + 0, 1u, __ATOMIC_RELEASE, __HIP_MEMORY_SCOPE_AGENT);
    if (c >= 8) return;
    if (tid == 0) {
        unsigned v;
        do {
            __builtin_amdgcn_s_sleep(8);
            v = __hip_atomic_load(gbar + 0, __ATOMIC_RELAXED, __HIP_MEMORY_SCOPE_AGENT);
        } while (v < 64u);
        (void)__hip_atomic_load(gbar + 0, __ATOMIC_ACQUIRE, __HIP_MEMORY_SCOPE_AGENT);
    }
    __syncthreads();

    // ---- L2: blocks 0-7 scan the group aggregates of their super ----
    scan8(64 * c + 7, 8);

    __syncthreads();
    if (tid == 0)
        __hip_atomic_fetch_add(gbar + 1, 1u, __ATOMIC_RELEASE, __HIP_MEMORY_SCOPE_AGENT);
    if (c != 0) return;
    if (tid == 0) {
        unsigned v;
        do {
            __builtin_amdgcn_s_sleep(8);
            v = __hip_atomic_load(gbar + 1, __ATOMIC_RELAXED, __HIP_MEMORY_SCOPE_AGENT);
        } while (v < 8u);
        (void)__hip_atomic_load(gbar + 1, __ATOMIC_ACQUIRE, __HIP_MEMORY_SCOPE_AGENT);
    }
    __syncthreads();

    // ---- s3 (block 0): E_{s+1} = P[64s+63]*E_s + V[64s+63] -> dead P32 slots
    // (reuses PB arrays as the E double-buffer)
    {
#pragma unroll
        for (int q = 0; q < 16; ++q) {
            int f = tid + q * 256; PBh[0][f >> 6][f & 63] = 0; PBl[0][f >> 6][f & 63] = 0;
        }
        uint4v rP[2][2]; float4 pV[4];
        {
            const unsigned* pc = P32 + (size_t)63 * 4096;
            const float*    vc = VT  + (size_t)63 * 4096;
#pragma unroll
            for (int kc = 0; kc < 2; ++kc) {
                const unsigned* p = pc + (size_t)arow*64 + 32*kc + 8*quad;
                rP[kc][0] = *(const uint4v*)p;
                rP[kc][1] = *(const uint4v*)(p + 4);
            }
#pragma unroll
            for (int ni = 0; ni < 4; ++ni)
                pV[ni] = *(const float4*)(vc + (size_t)(l15 + 16*ni)*64 + wr0);
        }
        __syncthreads();

        short8 aH[2], aL[2];
#pragma unroll
        for (int kc = 0; kc < 2; ++kc) unpack_frag(rP[kc][0], rP[kc][1], aH[kc], aL[kc]);

        int cur = 0;
        for (int s = 0; s < 7; ++s) {
            const int idx = 64 * s + 63;
            floatx4 acc[4];
#pragma unroll
            for (int ni = 0; ni < 4; ++ni) {
                acc[ni][0] = pV[ni].x; acc[ni][1] = pV[ni].y;
                acc[ni][2] = pV[ni].z; acc[ni][3] = pV[ni].w;
            }
            if (s + 1 < 7) {
                const int idx2 = 64 * (s + 1) + 63;
                const unsigned* pc = P32 + (size_t)idx2 * 4096;
                const float*    vc = VT  + (size_t)idx2 * 4096;
#pragma unroll
                for (int kc = 0; kc < 2; ++kc) {
                    const unsigned* p = pc + (size_t)arow*64 + 32*kc + 8*quad;
                    rP[kc][0] = *(const uint4v*)p;
                    rP[kc][1] = *(const uint4v*)(p + 4);
                }
#pragma unroll
                for (int ni = 0; ni < 4; ++ni)
                    pV[ni] = *(const float4*)(vc + (size_t)(l15 + 16*ni)*64 + wr0);
            }
#pragma unroll
            for (int kc = 0; kc < 2; ++kc) {
                const int ko = 32*kc + 8*quad;
#pragma unroll
                for (int ni = 0; ni < 4; ++ni) {
                    const int n = l15 + 16*ni;
                    short8 eH = *(const short8*)&PBh[cur][n][ko];
                    short8 eL = *(const short8*)&PBl[cur][n][ko];
                    acc[ni] = mfma_bf16(aH[kc], eH, acc[ni]);
                    acc[ni] = mfma_bf16(aH[kc], eL, acc[ni]);
                    acc[ni] = mfma_bf16(aL[kc], eH, acc[ni]);
                }
            }
            if (s + 1 < 7) {
#pragma unroll
                for (int kc = 0; kc < 2; ++kc) unpack_frag(rP[kc][0], rP[kc][1], aH[kc], aL[kc]);
            }
            float* eo = (float*)(P32 + (size_t)idx * 4096);
            const int nb = cur ^ 1;
#pragma unroll
            for (int ni = 0; ni < 4; ++ni) {
                const int cc = l15 + 16*ni;
                *(floatx4*)(eo + cc*64 + wr0) = acc[ni];
                if (s + 1 < 7) {
                    short4v h4, l4;
#pragma unroll
                    for (int r = 0; r < 4; ++r) { short hh,ll; split_bf16(acc[ni][r],hh,ll); h4[r]=hh; l4[r]=ll; }
                    *(short4v*)&PBh[nb][cc][wr0] = h4; *(short4v*)&PBl[nb][cc][wr0] = l4;
                }
            }
            if (s + 1 < 7) __syncthreads();
            cur ^= 1;
        }
    }
}

// ---------------------------------------------------------------------------
// Phase 3: entering state = (super E) combined with stored prefixes, then
// x <- A[t] x + u_t for 8 local steps.  A/P frags per-wave from global;
// X dbuf in LDS; one barrier per step/combine.
// ---------------------------------------------------------------------------
__global__ __launch_bounds__(256, 2)
void hippo_phase3(const float* __restrict__ inp, const float* __restrict__ Ag,
                  const float* __restrict__ Bst, const unsigned* __restrict__ P32,
                  const float* __restrict__ VT, float* __restrict__ out)
{
    __shared__ short XBh[2][NB][AS], XBl[2][NB][AS];

    const int tid = threadIdx.x, c = blockIdx.x, t0 = c * CH;
    const int w = tid >> 6, lane = tid & 63, quad = lane >> 4, l15 = lane & 15;
    const int arow = 16*w + l15;
    const int wr0  = 16*w + 4*quad;
    const int sup = c >> 6, g = c >> 3, gi = g & 7, j = c & 7;

    // issue A[t0] frag loads + b/i(t0) early (hide HBM under combines)
    float4 rA[2][2];
#pragma unroll
    for (int kc = 0; kc < 2; ++kc) {
        const float* p = Ag + (size_t)t0*4096 + (size_t)arow*64 + 32*kc + 8*quad;
        rA[kc][0] = *(const float4*)p;
        rA[kc][1] = *(const float4*)(p + 4);
    }
    float4 bcur = *(const float4*)(Bst + (size_t)t0*64 + wr0);
    float icur[4];
#pragma unroll
    for (int ni = 0; ni < 4; ++ni) icur[ni] = inp[(size_t)t0*64 + l15 + 16*ni];

    // ---- entering super state -> buf 0 ----
    if (sup == 0) {
#pragma unroll
        for (int q = 0; q < 16; ++q) { int f = tid + q*256; XBh[0][f>>6][f&63] = 0; XBl[0][f>>6][f&63] = 0; }
    } else {
        const float* e = (const float*)(P32 + (size_t)(64*(sup-1) + 63) * 4096);  // E_sup [b][n]
#pragma unroll
        for (int q = 0; q < 4; ++q) {
            int f = tid + q*256; int b = f>>4, k0 = (f&15)*4;
            float4 v = *(const float4*)(e + b*64 + k0);
            float va[4] = {v.x,v.y,v.z,v.w};
            short4v h4, l4;
#pragma unroll
            for (int r=0;r<4;++r){short hh,ll;split_bf16(va[r],hh,ll);h4[r]=hh;l4[r]=ll;}
            *(short4v*)&XBh[0][b][k0] = h4; *(short4v*)&XBl[0][b][k0] = l4;
        }
    }
    __syncthreads();
    int cur = 0;

    // ---- apply stored prefixes: X <- P[idx]*X + V[idx] ----
    auto combine = [&](int idx) {
        uint4v rP[2][2];
        const unsigned* pc = P32 + (size_t)idx * 4096;
        const float*    vc = VT  + (size_t)idx * 4096;
#pragma unroll
        for (int kc = 0; kc < 2; ++kc) {
            const unsigned* p = pc + (size_t)arow*64 + 32*kc + 8*quad;
            rP[kc][0] = *(const uint4v*)p;
            rP[kc][1] = *(const uint4v*)(p + 4);
        }
        floatx4 acc[4];
#pragma unroll
        for (int ni = 0; ni < 4; ++ni) {
            float4 vv = *(const float4*)(vc + (size_t)(l15 + 16*ni)*64 + wr0);
            acc[ni][0]=vv.x; acc[ni][1]=vv.y; acc[ni][2]=vv.z; acc[ni][3]=vv.w;
        }
        short8 cH[2], cL[2];
#pragma unroll
        for (int kc = 0; kc < 2; ++kc) unpack_frag(rP[kc][0], rP[kc][1], cH[kc], cL[kc]);
#pragma unroll
        for (int kc = 0; kc < 2; ++kc) {
            const int ko = 32*kc + 8*quad;
#pragma unroll
            for (int ni = 0; ni < 4; ++ni) {
                const int n = l15 + 16*ni;
                short8 xH = *(const short8*)&XBh[cur][n][ko];
                short8 xL = *(const short8*)&XBl[cur][n][ko];
                acc[ni] = mfma_bf16(cH[kc], xH, acc[ni]);
                acc[ni] = mfma_bf16(cH[kc], xL, acc[ni]);
                acc[ni] = mfma_bf16(cL[kc], xH, acc[ni]);
            }
        }
        const int nb = cur ^ 1;
#pragma unroll
        for (int ni = 0; ni < 4; ++ni) {
            const int cc = l15 + 16*ni;
            short4v h4, l4;
#pragma unroll
            for (int r=0;r<4;++r){short hh,ll;split_bf16(acc[ni][r],hh,ll);h4[r]=hh;l4[r]=ll;}
            *(short4v*)&XBh[nb][cc][wr0] = h4; *(short4v*)&XBl[nb][cc][wr0] = l4;
        }
        __syncthreads();
        cur ^= 1;
    };
    if (gi) combine(8*g - 1);   // in-super group prefix (L2 output)
    if (j)  combine(c - 1);     // in-group chunk prefix (L1 output)

    // convert A[t0] frags (loads issued at kernel start)
    short8 aH[2], aL[2];
#pragma unroll
    for (int kc = 0; kc < 2; ++kc) cvt_frag(rA[kc][0], rA[kc][1], aH[kc], aL[kc]);

    // ---- 8 local time steps ----
    float4 bnxt; float inxt[4];
    floatx4 acc[4];
    for (int s = 0; s < CH; ++s) {
        const int t = t0 + s;
        if (s + 1 < CH) {
            const int t1 = t + 1;
#pragma unroll
            for (int kc = 0; kc < 2; ++kc) {
                const float* p = Ag + (size_t)t1*4096 + (size_t)arow*64 + 32*kc + 8*quad;
                rA[kc][0] = *(const float4*)p;
                rA[kc][1] = *(const float4*)(p + 4);
            }
            bnxt = *(const float4*)(Bst + (size_t)t1*64 + wr0);
#pragma unroll
            for (int ni = 0; ni < 4; ++ni) inxt[ni] = inp[(size_t)t1*64 + l15 + 16*ni];
        }
        {
            float bc[4] = {bcur.x,bcur.y,bcur.z,bcur.w};
#pragma unroll
            for (int ni=0;ni<4;++ni)
#pragma unroll
            for (int r=0;r<4;++r) acc[ni][r] = bc[r] * icur[ni];
        }
#pragma unroll
        for (int kc = 0; kc < 2; ++kc) {
            const int ko = 32*kc + 8*quad;
#pragma unroll
            for (int ni = 0; ni < 4; ++ni) {
                const int n = l15 + 16*ni;
                short8 xH = *(const short8*)&XBh[cur][n][ko];
                short8 xL = *(const short8*)&XBl[cur][n][ko];
                acc[ni] = mfma_bf16(aH[kc], xH, acc[ni]);
                acc[ni] = mfma_bf16(aH[kc], xL, acc[ni]);
                acc[ni] = mfma_bf16(aL[kc], xH, acc[ni]);
            }
        }
        if (s + 1 < CH) {
#pragma unroll
            for (int kc = 0; kc < 2; ++kc) cvt_frag(rA[kc][0], rA[kc][1], aH[kc], aL[kc]);
        }
        const int nb = cur ^ 1;
#pragma unroll
        for (int ni = 0; ni < 4; ++ni) {
            const int cc = l15 + 16*ni;
            *(floatx4*)(out + (size_t)t*4096 + cc*64 + wr0) = acc[ni];   // out[t][b][n0..3]
            if (s + 1 < CH) {
                short4v h4, l4;
#pragma unroll
                for (int r=0;r<4;++r){short hh,ll;split_bf16(acc[ni][r],hh,ll);h4[r]=hh;l4[r]=ll;}
                *(short4v*)&XBh[nb][cc][wr0] = h4; *(short4v*)&XBl[nb][cc][wr0] = l4;
            }
        }
        if (s + 1 < CH) { __syncthreads(); cur ^= 1; }
        bcur = bnxt;
#pragma unroll
        for (int ni = 0; ni < 4; ++ni) icur[ni] = inxt[ni];
    }
}

extern "C" void kernel_launch(void* const* d_in, const int* in_sizes, int n_in,
                              void* d_out, int out_size, void* d_ws, size_t ws_size,
                              hipStream_t stream)
{
    const float* inp = (const float*)d_in[0];   // (L, B)
    const float* A   = (const float*)d_in[1];   // (L, N, N)
    const float* Bst = (const float*)d_in[2];   // (L, N)
    float* out = (float*)d_out;                  // (L, B, N)
    float* ws  = (float*)d_ws;

    unsigned* P32 = (unsigned*)ws;                   // 8 MB: packed hi|lo, row-major
    float*    VT  = (float*)ws + (size_t)CN * 4096;  // 8 MB: fp32, transposed
    unsigned* gbar = (unsigned*)((char*)d_ws + (size_t)16 * 1024 * 1024);  // 2 arrive counters

    hipMemsetAsync(gbar, 0, 2 * sizeof(unsigned), stream);
    hippo_phase1<<<CN, 256, 0, stream>>>(inp, A, Bst, P32, VT);
    hippo_scan<<<64, 256, 0, stream>>>(P32, VT, gbar);
    hippo_phase3<<<CN, 256, 0, stream>>>(inp, A, Bst, P32, VT, out);
}